// Round 16
// baseline (5075.714 us; speedup 1.0000x reference)
//
#include <hip/hip_runtime.h>
#include <hip/hip_bf16.h>

#define B_ 64
#define T_ 512
#define O_ 512
#define NWG 256
#define NTHR 256
#define EPSF 1e-5f

typedef __attribute__((ext_vector_type(8))) short short8v;
typedef __attribute__((ext_vector_type(4))) float f32x4;
typedef __attribute__((ext_vector_type(2))) float f32x2;
typedef __attribute__((ext_vector_type(4))) unsigned int u32x4;
typedef unsigned short u16;
typedef unsigned int u32;
typedef unsigned long long u64;

__device__ __forceinline__ u16 f2bf(float f) {
    union { float f; u32 u; } v; v.f = f;
    u32 r = v.u + 0x7fffu + ((v.u >> 16) & 1u);   // RNE
    return (u16)(r >> 16);
}
__device__ __forceinline__ float bf2f(u16 h) {
    union { u32 u; float f; } v; v.u = ((u32)h) << 16; return v.f;
}

// ---- sc1 (LLC-coherent, agent scope) helpers — relaxed, no fences, no RMW ----
__device__ __forceinline__ u32 ldg_sc1_u32(const u32* p) {
    return __hip_atomic_load(p, __ATOMIC_RELAXED, __HIP_MEMORY_SCOPE_AGENT);
}
__device__ __forceinline__ void stg_sc1_u32(u32* p, u32 v) {
    __hip_atomic_store(p, v, __ATOMIC_RELAXED, __HIP_MEMORY_SCOPE_AGENT);
}

// ---------- init: W fp32 [1024][2048] -> wt bf16 [2048 col][1024 k] ----------
__global__ void k_init_wt(const float* __restrict__ W, u16* __restrict__ wt) {
    __shared__ u16 tile[64][65];
    const int tk = (blockIdx.x >> 5) * 64;
    const int tn = (blockIdx.x & 31) * 64;
    const int r = threadIdx.x >> 6, c = threadIdx.x & 63;
#pragma unroll
    for (int i = 0; i < 16; ++i)
        tile[r + 4 * i][c] = f2bf(W[(size_t)(tk + r + 4 * i) * 2048 + tn + c]);
    __syncthreads();
#pragma unroll
    for (int i = 0; i < 16; ++i)
        wt[(size_t)(tn + r + 4 * i) * 1024 + tk + c] = tile[c][r + 4 * i];
}

// ---------- init: x fp32 [b][t][k] -> xbf bf16 [t][b][k] ----------
__global__ void k_init_x(const float* __restrict__ x, u16* __restrict__ xbf) {
    size_t e = ((size_t)blockIdx.x * 256 + threadIdx.x) * 8;
    int b = (int)(e >> 18);
    int r = (int)(e & 262143);
    int t = r >> 9, k = r & 511;
    float4 u0 = *(const float4*)(x + e);
    float4 u1 = *(const float4*)(x + e + 4);
    short8v v;
    v[0] = (short)f2bf(u0.x); v[1] = (short)f2bf(u0.y);
    v[2] = (short)f2bf(u0.z); v[3] = (short)f2bf(u0.w);
    v[4] = (short)f2bf(u1.x); v[5] = (short)f2bf(u1.y);
    v[6] = (short)f2bf(u1.z); v[7] = (short)f2bf(u1.w);
    *(short8v*)(xbf + ((size_t)t * B_ + b) * 512 + k) = v;
}

__global__ void k_zero_flags(u32* grpfl) {
    int gid = blockIdx.x * 256 + threadIdx.x;
    if (gid < 512) stg_sc1_u32(grpfl + gid, 0u);
}

// ---------- persistent LN-LSTM: 8 groups x 32 wgs, point-to-point flags ----------
// wg (grp=wgid&7, slot=wgid>>3) owns cols {512w+16slot+rl} (wave w = gate w),
// batch rows grp*8..+8.  Per step: hGEMM(LDS) -> comb slice (bf16 pairs,
// [pair][row][gate] layout, parity-double-buffered) -> per-wg flag -> each
// consumer THREAD polls only its single producer's flag, gathers 128 B
// contiguous -> wg-internal stats reduce -> redundant gates/c/h -> h into own
// LDS tile.  h never crosses memory; no global barrier, only p2p flags.
__global__ __launch_bounds__(NTHR, 1)
void k_persist(const u16* __restrict__ xbf, const u16* __restrict__ wt,
               const float* __restrict__ bias, const float* __restrict__ lnw,
               const float* __restrict__ lnb, const float* __restrict__ hx,
               const float* __restrict__ cx, u32* comb, u32* grpfl,
               float* __restrict__ out) {
    __shared__ u16 hT[4096];          // [8 rows][512] bf16, XOR-swizzled (G4)
    __shared__ f32x2 sp[4][8];        // per-wave (S,Q) partials per row
    __shared__ f32x2 sstat[8];        // reduced (S,Q) per row

    const int tid = threadIdx.x, wgid = blockIdx.x;
    const int grp = wgid & 7, slot = wgid >> 3;
    const int w = tid >> 6, l = tid & 63;
    const int rl = l & 15, kg = l >> 4;
    const int arow = rl & 7;                    // A-row this lane loads
    char* hTB = (char*)hT;
    u32* gf = grpfl + grp * 64;                 // 32 slot flags per group
    const int myprod = tid >> 3;                // the ONE producer this thread reads

    // ---- W fragments into registers (16 cols x full K per wave) ----
    const int mycol = 512 * w + 16 * slot + rl;
    short8v bw[32];
#pragma unroll
    for (int kc = 0; kc < 32; ++kc)
        bw[kc] = *(const short8v*)(wt + (size_t)mycol * 1024 + kc * 32 + kg * 8);
    const float bcol = bias[mycol];

    // ---- gate-lane identity: thread owns outputs {po2, po2+1} for ALL 8 rows ----
    const int po2 = tid * 2;
    float lwv[8], lbv[8];
#pragma unroll
    for (int g = 0; g < 4; ++g) {
        lwv[g * 2]     = lnw[g * 512 + po2];
        lwv[g * 2 + 1] = lnw[g * 512 + po2 + 1];
        lbv[g * 2]     = lnb[g * 512 + po2];
        lbv[g * 2 + 1] = lnb[g * 512 + po2 + 1];
    }
    float c16[16];
    {
        float c0 = cx[po2], c1 = cx[po2 + 1];
#pragma unroll
        for (int r = 0; r < 8; ++r) { c16[r * 2] = c0; c16[r * 2 + 1] = c1; }
        u32 hp = (u32)f2bf(hx[po2]) | ((u32)f2bf(hx[po2 + 1]) << 16);
#pragma unroll
        for (int r = 0; r < 8; ++r)                  // h0 (same for all rows)
            *(u32*)(hTB + ((r * 1024 + po2 * 2) ^ (r << 4))) = hp;
    }
    __syncthreads();

    // ---- x-half GEMM: bf16 cached loads, K 0..511 ----
    auto xgemm = [&](int t, f32x4& c0, f32x4& c1) {
        const u16* xr = xbf + ((size_t)t * B_ + grp * 8 + arow) * 512;
#pragma unroll
        for (int kc = 0; kc < 16; ++kc) {
            short8v a = *(const short8v*)(xr + kc * 32 + kg * 8);
            if (kc & 1) c1 = __builtin_amdgcn_mfma_f32_16x16x32_bf16(a, bw[kc], c1, 0, 0, 0);
            else        c0 = __builtin_amdgcn_mfma_f32_16x16x32_bf16(a, bw[kc], c0, 0, 0, 0);
        }
    };

    f32x4 xa0 = {0.f, 0.f, 0.f, 0.f}, xa1 = {0.f, 0.f, 0.f, 0.f};
    xgemm(0, xa0, xa1);

    for (int t = 0; t < T_; ++t) {
        // ===== phase 1: h-half GEMM from own LDS (swizzled b128 reads) =====
#pragma unroll
        for (int kc = 0; kc < 16; ++kc) {
            int byte = arow * 1024 + kc * 64 + kg * 16;
            short8v a = *(const short8v*)(hTB + (byte ^ (arow << 4)));
            if (kc & 1) xa1 = __builtin_amdgcn_mfma_f32_16x16x32_bf16(a, bw[16 + kc], xa1, 0, 0, 0);
            else        xa0 = __builtin_amdgcn_mfma_f32_16x16x32_bf16(a, bw[16 + kc], xa0, 0, 0, 0);
        }
        f32x4 acc = xa0 + xa1;

        const int cb = t & 1;                       // parity double buffer
        u32* combB = comb + (size_t)cb * 65536 + (size_t)grp * 8192;  // [pair][row][gate]

        // ---- publish comb slice: bf16 pairs into [pair][row][gate] ----
        float v4[4], vo[4];
#pragma unroll
        for (int j = 0; j < 4; ++j) v4[j] = acc[j] + bcol;
#pragma unroll
        for (int j = 0; j < 4; ++j) vo[j] = __shfl_xor(v4[j], 1);   // col-pair mate
        if (kg < 2 && !(rl & 1)) {                  // rows 0..7, even col of pair
            int pair = slot * 8 + (rl >> 1);
#pragma unroll
            for (int j = 0; j < 4; ++j) {
                u32 pk = (u32)f2bf(v4[j]) | ((u32)f2bf(vo[j]) << 16);
                stg_sc1_u32(combB + pair * 32 + (kg * 4 + j) * 4 + w, pk);
            }
        }
        asm volatile("s_waitcnt vmcnt(0)" ::: "memory");   // own stores at LLC
        __syncthreads();                                   // all lanes' stores drained
        if (tid == 0) stg_sc1_u32(gf + slot, (u32)(t + 1));

        // overlap flag propagation with next step's x-GEMM
        if (t + 1 < T_) {
            xa0 = f32x4{0.f, 0.f, 0.f, 0.f}; xa1 = f32x4{0.f, 0.f, 0.f, 0.f};
            xgemm(t + 1, xa0, xa1);
        }

        // ===== p2p wait: poll ONLY my producer's flag, then gather 128 B =====
        while (ldg_sc1_u32(gf + myprod) < (u32)(t + 1)) {}
        u32x4 cg[8];
        {
            const u32* gbase = combB + tid * 32;
#pragma unroll
            for (int r = 0; r < 8; ++r)
                asm volatile("global_load_dwordx4 %0, %1, off sc1"
                             : "=v"(cg[r]) : "v"(gbase + r * 4) : "memory");
            asm volatile("s_waitcnt vmcnt(0)" ::: "memory");
            __builtin_amdgcn_sched_barrier(0);             // rule #18
        }

        // ===== wg-internal stats from gathered bf16 comb =====
        float s8[8], q8[8];
#pragma unroll
        for (int r = 0; r < 8; ++r) {
            float s = 0.f, q = 0.f;
#pragma unroll
            for (int g = 0; g < 4; ++g) {
#pragma unroll
                for (int i = 0; i < 2; ++i) {
                    float v = bf2f((u16)(cg[r][g] >> (16 * i)));
                    s += v; q += v * v;
                }
            }
            s8[r] = s; q8[r] = q;
        }
#pragma unroll
        for (int m = 1; m < 64; m <<= 1) {
#pragma unroll
            for (int r = 0; r < 8; ++r) {
                s8[r] += __shfl_xor(s8[r], m);
                q8[r] += __shfl_xor(q8[r], m);
            }
        }
        if (l == 0) {
#pragma unroll
            for (int r = 0; r < 8; ++r) sp[w][r] = f32x2{s8[r], q8[r]};
        }
        __syncthreads();
        if (tid < 8)
            sstat[tid] = f32x2{sp[0][tid].x + sp[1][tid].x + sp[2][tid].x + sp[3][tid].x,
                               sp[0][tid].y + sp[1][tid].y + sp[2][tid].y + sp[3][tid].y};
        __syncthreads();

        // ===== redundant gates/c/h for my 8 rows =====
#pragma unroll
        for (int r = 0; r < 8; ++r) {
            float S = sstat[r].x, Q = sstat[r].y;
            float mu = S * (1.0f / 2048.0f);
            float var = Q * (1.0f / 2048.0f) - mu * mu;
            float rstd = rsqrtf(var + EPSF);
            float hh[2];
#pragma unroll
            for (int i = 0; i < 2; ++i) {
                float cv0 = bf2f((u16)(cg[r][0] >> (16 * i)));
                float cv1 = bf2f((u16)(cg[r][1] >> (16 * i)));
                float cv2 = bf2f((u16)(cg[r][2] >> (16 * i)));
                float cv3 = bf2f((u16)(cg[r][3] >> (16 * i)));
                float g0 = (cv0 - mu) * rstd * lwv[0 + i] + lbv[0 + i];
                float g1 = (cv1 - mu) * rstd * lwv[2 + i] + lbv[2 + i];
                float g2 = (cv2 - mu) * rstd * lwv[4 + i] + lbv[4 + i];
                float g3 = (cv3 - mu) * rstd * lwv[6 + i] + lbv[6 + i];
                float ig = 1.f / (1.f + __expf(-g0));
                float fg = 1.f / (1.f + __expf(-g1));
                float og = 1.f / (1.f + __expf(-g2));
                float e2 = __expf(-2.f * fabsf(g3));
                float th = copysignf((1.f - e2) / (1.f + e2), g3);
                float cc = fg * c16[r * 2 + i] + ig * th;
                c16[r * 2 + i] = cc;
                hh[i] = og * cc;
            }
            u32 hp = (u32)f2bf(hh[0]) | ((u32)f2bf(hh[1]) << 16);
            *(u32*)(hTB + ((r * 1024 + po2 * 2) ^ (r << 4))) = hp;   // h(t+1) tile
            if (slot == 0) {                        // one wg per group writes out
                f32x2 ho{hh[0], hh[1]};
                __builtin_nontemporal_store(ho,
                    (f32x2*)(out + (size_t)(grp * 8 + r) * (T_ * O_) + (size_t)t * O_ + po2));
            }
        }
        __syncthreads();                            // hT ready for next h-GEMM
    }
}

extern "C" void kernel_launch(void* const* d_in, const int* in_sizes, int n_in,
                              void* d_out, int out_size, void* d_ws, size_t ws_size,
                              hipStream_t stream) {
    const float* x    = (const float*)d_in[0];
    const float* W    = (const float*)d_in[1];
    const float* bias = (const float*)d_in[2];
    const float* lnw  = (const float*)d_in[3];
    const float* lnb  = (const float*)d_in[4];
    const float* hx   = (const float*)d_in[5];
    const float* cx   = (const float*)d_in[6];
    float* out = (float*)d_out;

    char* ws = (char*)d_ws;
    u16*   wt    = (u16*)ws;                      // [0        .. 4194304)
    u16*   xbf   = (u16*)(ws + 4194304);          // [4194304  .. 37748736)
    u32*   comb  = (u32*)(ws + 37748736);         // [37748736 .. 38273024)  512 KiB
    u32*   grpfl = (u32*)(ws + 38273024);         // [38273024 .. 38275072)    2 KiB
    // total 38275072 B < 38797312 B proven budget; regions disjoint.

    k_init_wt<<<512, 256, 0, stream>>>(W, wt);
    k_init_x<<<8192, 256, 0, stream>>>(x, xbf);
    k_zero_flags<<<2, 256, 0, stream>>>(grpfl);
    k_persist<<<NWG, NTHR, 0, stream>>>(xbf, wt, bias, lnw, lnb, hx, cx,
                                        comb, grpfl, out);
}